// Round 6
// baseline (184.547 us; speedup 1.0000x reference)
//
#include <hip/hip_runtime.h>
#include <hip/hip_bf16.h>
#include <stdint.h>

typedef __attribute__((ext_vector_type(8))) short short8;
typedef __attribute__((ext_vector_type(4))) float float4v;

#define SEQ   1024
#define NQKV  3072

__device__ __forceinline__ float bf2f(ushort h) {
    union { uint u; float f; } c; c.u = ((uint)h) << 16; return c.f;
}
__device__ __forceinline__ ushort f2bf(float f) {
    union { uint u; float f; } c; c.f = f;
    uint u = c.u;
    return (ushort)((u + 0x7fffu + ((u >> 16) & 1u)) >> 16);
}
__device__ __forceinline__ uint cvt_pk_bf16(float lo, float hi) {
    uint r;
    asm volatile("v_cvt_pk_bf16_f32 %0, %1, %2" : "=v"(r) : "v"(lo), "v"(hi));
    return r;
}
__device__ __forceinline__ void gl2lds16(const ushort* g, ushort* l) {
    __builtin_amdgcn_global_load_lds(
        (const __attribute__((address_space(1))) unsigned int*)(g),
        (__attribute__((address_space(3))) unsigned int*)(l),
        16, 0, 0);
}

#define FENCE() asm volatile("" ::: "memory")
#define PBAR()  do { FENCE(); __builtin_amdgcn_s_barrier(); FENCE(); } while (0)

// ---------------------------------------------------------------------------
// prep_k: fused detect + X-convert + bias-concat + 4x weight transpose.
// ---------------------------------------------------------------------------
__global__ __launch_bounds__(256) void prep_k(const void* __restrict__ X,
                                              const void* __restrict__ w0,
                                              const void* __restrict__ w1,
                                              const void* __restrict__ w2,
                                              const void* __restrict__ w3,
                                              const void* __restrict__ bq,
                                              const void* __restrict__ bk,
                                              const void* __restrict__ bv,
                                              const void* __restrict__ bo,
                                              ushort* __restrict__ xc,
                                              ushort* __restrict__ biasout,
                                              ushort* __restrict__ wtall,
                                              int* __restrict__ flag) {
    __shared__ int tot;
    __shared__ ushort tile[64][72];
    int t = threadIdx.x;
    if (t == 0) tot = 0;
    __syncthreads();
    uint wv = ((const uint*)X)[t];
    uint e = (wv >> 7) & 0xFFu;
    bool isbf = (e >= 100u && e <= 130u);
    unsigned long long m = __ballot(isbf);
    if ((t & 63) == 0) atomicAdd(&tot, __popcll(m));
    __syncthreads();
    bool isf = (tot <= 128);   // true -> fp32 input

    int bi = blockIdx.x;
    if (bi == 0 && t == 0) flag[0] = isf ? 1 : 0;

    if (bi < 4096) {
        if (!isf) return;
        int i = (bi * 256 + t) * 4;
        float4 v = *(const float4*)((const float*)X + i);
        ushort4 o;
        o.x = f2bf(v.x); o.y = f2bf(v.y); o.z = f2bf(v.z); o.w = f2bf(v.w);
        *(ushort4*)(xc + i) = o;
    } else if (bi < 4112) {
        int i = (bi - 4096) * 256 + t;
        int sel = i >> 10, j = i & 1023;
        const void* p = (sel == 0) ? bq : (sel == 1) ? bk : (sel == 2) ? bv : bo;
        biasout[i] = isf ? f2bf(((const float*)p)[j]) : ((const ushort*)p)[j];
    } else {
        int idx = bi - 4112;
        int z = idx >> 8, rem = idx & 255;
        const void* in = (z == 0) ? w0 : (z == 1) ? w1 : (z == 2) ? w2 : w3;
        ushort* out = wtall + (size_t)z * 1024 * 1024;
        int k0 = (rem & 15) * 64, n0 = (rem >> 4) * 64;
        int r = t >> 3, c = (t & 7) * 8;
#pragma unroll
        for (int p = 0; p < 2; p++) {
            int rr = r + p * 32;
            if (isf) {
                const float* src = (const float*)in + (size_t)(k0 + rr) * 1024 + n0 + c;
                float4 v0 = *(const float4*)src;
                float4 v1 = *(const float4*)(src + 4);
                tile[rr][c + 0] = f2bf(v0.x); tile[rr][c + 1] = f2bf(v0.y);
                tile[rr][c + 2] = f2bf(v0.z); tile[rr][c + 3] = f2bf(v0.w);
                tile[rr][c + 4] = f2bf(v1.x); tile[rr][c + 5] = f2bf(v1.y);
                tile[rr][c + 6] = f2bf(v1.z); tile[rr][c + 7] = f2bf(v1.w);
            } else {
                uint4 v = *(const uint4*)((const ushort*)in + (size_t)(k0 + rr) * 1024 + n0 + c);
                *(uint4*)&tile[rr][c] = v;
            }
        }
        __syncthreads();
#pragma unroll
        for (int p = 0; p < 2; p++) {
            int n = r + p * 32;
            ushort vals[8];
#pragma unroll
            for (int j = 0; j < 8; j++) vals[j] = tile[c + j][n];
            *(uint4*)(out + (size_t)(n0 + n) * 1024 + k0 + c) = *(uint4*)vals;
        }
    }
}

// ---------------------------------------------------------------------------
// gemm256_k: QKV GEMM, 256x256 tile, BK=64, 8 waves (2M x 4N), counted-vmcnt
// 4-phase schedule (T2+T3+T4). M=4096 N=3072 K=1024 fixed.
// Phases per K-tile group j (quadrants of the wave's 128x64 output):
//   ph1 (Msub0,Nlo): 12 ds_read | stage B0(j+1) | 16 MFMA | barrier
//   ph2 (Msub0,Nhi):  4 ds_read | stage B1(j+1) | 16 MFMA | barrier
//   ph3 (Msub1,Nhi):  8 ds_read | stage A0(j+2) | 16 MFMA | barrier
//   ph4 (Msub1,Nlo):  0 ds_read | stage A1(j+2) | 16 MFMA | vmcnt(4) | barrier
// Safety (derived, block-wide via end-of-phase barriers):
//   A-half h of buf[cur] fully read after ph(1+2h); B-half fully read after
//   ph2 (each wave reads only its own 64-col slice, lo@ph1 hi@ph2, regs
//   reused ph3/ph4). vmcnt(4) before the ph4 barrier completes all stages
//   except the last 2 half-tiles -> everything group j+1 reads has landed.
//   Tail: j=14 uses vmcnt(0) (A-stages skipped, only 4 loads outstanding).
// LDS swizzle: chunk slot = L ^ (row&7) (R4-verified, 0 bank conflicts).
// K accumulation order identical to the 2-phase kernel -> same absmax.
// WRV: n0 >= 2048 blocks also emit VT[bh][d][t] from the accumulator.
// ---------------------------------------------------------------------------
__device__ __forceinline__ void stage_half(const ushort* src, int K, ushort* lds, int t) {
#pragma unroll
    for (int jj = 0; jj < 2; jj++) {
        int c = jj * 512 + t;
        int row = c >> 3, s = c & 7;
        int kc = s ^ (row & 7);
        gl2lds16(src + (size_t)row * K + kc * 8, lds + c * 8);
    }
}

__global__ __launch_bounds__(512, 2) void gemm256_k(const ushort* __restrict__ Araw,
                                                    const ushort* __restrict__ Aconv,
                                                    const ushort* __restrict__ BT,
                                                    const ushort* __restrict__ bias,
                                                    ushort* __restrict__ C,
                                                    ushort* __restrict__ vt,
                                                    const int* __restrict__ flag) {
    constexpr int K = 1024;
    constexpr int N = NQKV;
    __shared__ ushort As[2][256 * 64];
    __shared__ ushort Bs[2][256 * 64];
    int orig = blockIdx.y * gridDim.x + blockIdx.x;     // 192 blocks
    int swz = (orig & 7) * 24 + (orig >> 3);            // XCD swizzle (192%8==0)
    int n0 = (swz % 12) * 256, m0 = (swz / 12) * 256;
    int t = threadIdx.x;
    int w = t >> 6, lane = t & 63, q = lane >> 4, ln = lane & 15;
    int wr = w & 1, wc = w >> 1;                        // 2M x 4N waves
    const ushort* A = (*flag) ? Aconv : Araw;

    float4v acc[8][4];
#pragma unroll
    for (int r = 0; r < 8; r++)
#pragma unroll
        for (int cc = 0; cc < 4; cc++) acc[r][cc] = (float4v){0.f, 0.f, 0.f, 0.f};

    // prologue: kt0 (all 4 half-tiles) + kt1 A-halves; B(1) staged in group 0
    stage_half(A  + (size_t)m0 * K,           K, &As[0][0], t);
    stage_half(A  + (size_t)(m0 + 128) * K,   K, &As[0][128 * 64], t);
    stage_half(BT + (size_t)n0 * K,           K, &Bs[0][0], t);
    stage_half(BT + (size_t)(n0 + 128) * K,   K, &Bs[0][128 * 64], t);
    stage_half(A  + (size_t)m0 * K + 64,      K, &As[1][0], t);
    stage_half(A  + (size_t)(m0 + 128) * K + 64, K, &As[1][128 * 64], t);
    asm volatile("s_waitcnt vmcnt(4)" ::: "memory");
    PBAR();

    short8 af[4][2];        // current Msub A-frags [mf][kh]
    short8 bf[2][2][2];     // [nsub][nf][kh]

    for (int j = 0; j < 16; j++) {
        int cur = j & 1;
        int nxt = cur ^ 1;
        // ---- ph1: Msub0 x Nlo ----
#pragma unroll
        for (int mf = 0; mf < 4; mf++)
#pragma unroll
            for (int kh = 0; kh < 2; kh++) {
                int r = wr * 64 + mf * 16 + ln;
                af[mf][kh] = *(const short8*)&As[cur][(r * 8 + ((kh * 4 + q) ^ (r & 7))) * 8];
            }
#pragma unroll
        for (int nf = 0; nf < 2; nf++)
#pragma unroll
            for (int kh = 0; kh < 2; kh++) {
                int rb = wc * 64 + nf * 16 + ln;
                bf[0][nf][kh] = *(const short8*)&Bs[cur][(rb * 8 + ((kh * 4 + q) ^ (rb & 7))) * 8];
            }
        if (j + 1 < 16) stage_half(BT + (size_t)n0 * K + (j + 1) * 64, K, &Bs[nxt][0], t);
#pragma unroll
        for (int mf = 0; mf < 4; mf++)
#pragma unroll
            for (int nf = 0; nf < 2; nf++)
#pragma unroll
                for (int kh = 0; kh < 2; kh++)
                    acc[mf][nf] = __builtin_amdgcn_mfma_f32_16x16x32_bf16(af[mf][kh], bf[0][nf][kh], acc[mf][nf], 0, 0, 0);
        PBAR();
        // ---- ph2: Msub0 x Nhi ----
#pragma unroll
        for (int nf = 0; nf < 2; nf++)
#pragma unroll
            for (int kh = 0; kh < 2; kh++) {
                int rb = wc * 64 + 32 + nf * 16 + ln;
                bf[1][nf][kh] = *(const short8*)&Bs[cur][(rb * 8 + ((kh * 4 + q) ^ (rb & 7))) * 8];
            }
        if (j + 1 < 16) stage_half(BT + (size_t)(n0 + 128) * K + (j + 1) * 64, K, &Bs[nxt][128 * 64], t);
#pragma unroll
        for (int mf = 0; mf < 4; mf++)
#pragma unroll
            for (int nf = 0; nf < 2; nf++)
#pragma unroll
                for (int kh = 0; kh < 2; kh++)
                    acc[mf][2 + nf] = __builtin_amdgcn_mfma_f32_16x16x32_bf16(af[mf][kh], bf[1][nf][kh], acc[mf][2 + nf], 0, 0, 0);
        PBAR();
        // ---- ph3: Msub1 x Nhi ----
#pragma unroll
        for (int mf = 0; mf < 4; mf++)
#pragma unroll
            for (int kh = 0; kh < 2; kh++) {
                int r = 128 + wr * 64 + mf * 16 + ln;
                af[mf][kh] = *(const short8*)&As[cur][(r * 8 + ((kh * 4 + q) ^ (r & 7))) * 8];
            }
        if (j + 2 < 16) stage_half(A + (size_t)m0 * K + (j + 2) * 64, K, &As[cur][0], t);
#pragma unroll
        for (int mf = 0; mf < 4; mf++)
#pragma unroll
            for (int nf = 0; nf < 2; nf++)
#pragma unroll
                for (int kh = 0; kh < 2; kh++)
                    acc[4 + mf][2 + nf] = __builtin_amdgcn_mfma_f32_16x16x32_bf16(af[mf][kh], bf[1][nf][kh], acc[4 + mf][2 + nf], 0, 0, 0);
        PBAR();
        // ---- ph4: Msub1 x Nlo (regs only) ----
        if (j + 2 < 16) stage_half(A + (size_t)(m0 + 128) * K + (j + 2) * 64, K, &As[cur][128 * 64], t);
#pragma unroll
        for (int mf = 0; mf < 4; mf++)
#pragma unroll
            for (int nf = 0; nf < 2; nf++)
#pragma unroll
                for (int kh = 0; kh < 2; kh++)
                    acc[4 + mf][nf] = __builtin_amdgcn_mfma_f32_16x16x32_bf16(af[mf][kh], bf[0][nf][kh], acc[4 + mf][nf], 0, 0, 0);
        if (j < 14) { asm volatile("s_waitcnt vmcnt(4)" ::: "memory"); }
        else        { asm volatile("s_waitcnt vmcnt(0)" ::: "memory"); }
        PBAR();
    }

    bool wrv = (n0 >= 2048);
#pragma unroll
    for (int nfull = 0; nfull < 4; nfull++) {
        int n = n0 + wc * 64 + nfull * 16 + ln;
        float bs = bf2f(bias[n]);
#pragma unroll
        for (int m8 = 0; m8 < 8; m8++) {
            ushort pk[4];
#pragma unroll
            for (int i = 0; i < 4; i++) {
                int m = m0 + (m8 >> 2) * 128 + wr * 64 + (m8 & 3) * 16 + q * 4 + i;
                float v = acc[m8][nfull][i] + bs;
                C[(size_t)m * N + n] = f2bf(v);
                pk[i] = f2bf(v);
            }
            if (wrv) {
                int mb = m0 + (m8 >> 2) * 128 + wr * 64 + (m8 & 3) * 16 + q * 4;
                int b = mb >> 10, trow = mb & 1023;
                int h = (n - 2048) >> 6, d = n & 63;
                *(ushort4*)(vt + (((size_t)(b * 16 + h) * 64 + d) * 1024 + trow)) = *(ushort4*)pk;
            }
        }
    }
}

// ---------------------------------------------------------------------------
// GEMM, BK=32 DOUBLE-BUFFERED, single barrier per K-iter, BM x 128 tile,
// 4 waves (2x2). Used for the output projection. BK=32 deliberate (R4:
// BK=64 dropped occupancy and regressed). XCD swizzle (nwg%8==0).
// ---------------------------------------------------------------------------
template <int BM, bool DUAL, bool WRV>
__global__ __launch_bounds__(256) void gemm_k(const ushort* __restrict__ Araw,
                                              const ushort* __restrict__ Aconv,
                                              const ushort* __restrict__ BT,
                                              const ushort* __restrict__ bias,
                                              void* __restrict__ C,
                                              ushort* __restrict__ vt,
                                              const int* __restrict__ flag,
                                              int M, int N, int K) {
    constexpr int RM = BM / 32;   // M-frags per wave
    constexpr int AJ = BM / 64;   // A-chunks per thread (BM*4/256)
    __shared__ ushort As[2][BM * 32];
    __shared__ ushort Bs[2][128 * 32];
    int nwgx = gridDim.x;
    int orig = blockIdx.y * nwgx + blockIdx.x;
    int cpx = (nwgx * gridDim.y) >> 3;
    int swz = (orig & 7) * cpx + (orig >> 3);
    int n0 = (swz % nwgx) * 128, m0 = (swz / nwgx) * BM;
    int t = threadIdx.x;
    int w = t >> 6, lane = t & 63, q = lane >> 4, ln = lane & 15;
    int wr = w >> 1, wc = w & 1;
    const ushort* A = (*flag) ? Aconv : Araw;

    float4v acc[RM][4];
#pragma unroll
    for (int r = 0; r < RM; r++)
#pragma unroll
        for (int cc = 0; cc < 4; cc++) acc[r][cc] = (float4v){0.f, 0.f, 0.f, 0.f};

    // prologue: stage k0=0 into buf 0
#pragma unroll
    for (int j = 0; j < AJ; j++) {
        int c = j * 256 + t;
        int row = c >> 2, s = c & 3;
        int kc = s ^ ((row >> 1) & 3);
        gl2lds16(A + (size_t)(m0 + row) * K + kc * 8, &As[0][c * 8]);
    }
#pragma unroll
    for (int j = 0; j < 2; j++) {
        int c = j * 256 + t;
        int row = c >> 2, s = c & 3;
        int kc = s ^ ((row >> 1) & 3);
        gl2lds16(BT + (size_t)(n0 + row) * K + kc * 8, &Bs[0][c * 8]);
    }

    int nIter = K >> 5;
    for (int kt = 0; kt < nIter; kt++) {
        int cur = kt & 1;
        __syncthreads();   // buf[cur] staged; buf[cur^1] reads complete
        if (kt + 1 < nIter) {
            int nk0 = (kt + 1) << 5, nxt = cur ^ 1;
#pragma unroll
            for (int j = 0; j < AJ; j++) {
                int c = j * 256 + t;
                int row = c >> 2, s = c & 3;
                int kc = s ^ ((row >> 1) & 3);
                gl2lds16(A + (size_t)(m0 + row) * K + nk0 + kc * 8, &As[nxt][c * 8]);
            }
#pragma unroll
            for (int j = 0; j < 2; j++) {
                int c = j * 256 + t;
                int row = c >> 2, s = c & 3;
                int kc = s ^ ((row >> 1) & 3);
                gl2lds16(BT + (size_t)(n0 + row) * K + nk0 + kc * 8, &Bs[nxt][c * 8]);
            }
        }
        short8 af[RM], bf[4];
#pragma unroll
        for (int r = 0; r < RM; r++) {
            int row = wr * (BM / 2) + r * 16 + ln;
            af[r] = *(const short8*)&As[cur][((row << 2) | (q ^ ((row >> 1) & 3))) * 8];
        }
#pragma unroll
        for (int cc = 0; cc < 4; cc++) {
            int col = wc * 64 + cc * 16 + ln;
            bf[cc] = *(const short8*)&Bs[cur][((col << 2) | (q ^ ((col >> 1) & 3))) * 8];
        }
#pragma unroll
        for (int r = 0; r < RM; r++)
#pragma unroll
            for (int cc = 0; cc < 4; cc++)
                acc[r][cc] = __builtin_amdgcn_mfma_f32_16x16x32_bf16(af[r], bf[cc], acc[r][cc], 0, 0, 0);
    }

    bool outf = DUAL && (*flag != 0);
    bool wrv = WRV && (n0 >= 2048);
#pragma unroll
    for (int cc = 0; cc < 4; cc++) {
        int n = n0 + wc * 64 + cc * 16 + ln;
        float bs = bf2f(bias[n]);
#pragma unroll
        for (int r = 0; r < RM; r++) {
            ushort pk[4];
#pragma unroll
            for (int i = 0; i < 4; i++) {
                int m = m0 + wr * (BM / 2) + r * 16 + q * 4 + i;
                float v = acc[r][cc][i] + bs;
                if (outf) ((float*)C)[(size_t)m * N + n] = v;
                else      ((ushort*)C)[(size_t)m * N + n] = f2bf(v);
                pk[i] = f2bf(v);
            }
            if (wrv) {
                int mb = m0 + wr * (BM / 2) + r * 16 + q * 4;
                int b = mb >> 10, trow = mb & 1023;
                int h = (n - 2048) >> 6, d = n & 63;
                *(ushort4*)(vt + (((size_t)(b * 16 + h) * 64 + d) * 1024 + trow)) = *(ushort4*)pk;
            }
        }
    }
}

// ---------------------------------------------------------------------------
// Flash attention, causal, WAVE-SPLIT shared-prefix dual-tile (pr, 15-pr),
// pipelined, no-max softmax. Balanced: 17 active wave-group iters per block;
// CU-pairing balance via pr = 7-x relabel for bh>=32 (R5-verified).
// SWAPPED QK^T (T12); P-write via v_cvt_pk_bf16_f32 pairs.
// Faithful reshape: z[b,h,s,d] -> Z'[b][h*64 + s/16][(s%16)*64 + d]
// ---------------------------------------------------------------------------
__global__ __launch_bounds__(512) void attn_k(const ushort* __restrict__ qkv,
                                              const ushort* __restrict__ vt,
                                              ushort* __restrict__ zp) {
    __shared__ ushort Ks[2][64 * 64];
    __shared__ ushort Vs[2][64 * 64];
    __shared__ ushort P[8][16 * 76];
    int bh = blockIdx.y;
    int pr = (bh & 32) ? (7 - blockIdx.x) : blockIdx.x;
    int b = bh >> 4, h = bh & 15;
    int t = threadIdx.x;
    int w = t >> 6;
    int grp = w >> 2;
    int lane = t & 63, q = lane >> 4, ln = lane & 15;

    const float CE = 0.72134752f;    // 0.5 * log2(e)

    const ushort* Qp = qkv + (size_t)(b * SEQ) * NQKV + h * 64;
    const ushort* Kp = qkv + (size_t)(b * SEQ) * NQKV + 1024 + h * 64;
    const ushort* Vt = vt + (size_t)bh * 64 * 1024;

    int row0 = t >> 3, kc0 = (t & 7) ^ (row0 & 7);

    int tiB = 15 - pr;
    int ti = grp ? tiB : pr;
    int sw = ti * 64 + (w & 3) * 16;

    short8 aq0 = *(const short8*)(Qp + (size_t)(sw + ln) * NQKV + q * 8);
    short8 aq1 = *(const short8*)(Qp + (size_t)(sw + ln) * NQKV + 32 + q * 8);

    float lp = 0.f;
    float4v o[4];
#pragma unroll
    for (int nb = 0; nb < 4; nb++) o[nb] = (float4v){0.f, 0.f, 0.f, 0.f};

    gl2lds16(Kp + (size_t)row0 * NQKV + kc0 * 8, &Ks[0][t * 8]);
    gl2lds16(Vt + (size_t)row0 * 1024 + kc0 * 8, &Vs[0][t * 8]);

    int srow_l = sw + ln;   // this lane's q-row (post-swap: srow = ln axis)

    for (int kt = 0; kt <= tiB; kt++) {
        int cur = kt & 1;
        int t0 = kt * 64;
        __syncthreads();
        if (kt < tiB) {
            int nt0 = t0 + 64, nxt = cur ^ 1;
            gl2lds16(Kp + (size_t)(nt0 + row0) * NQKV + kc0 * 8, &Ks[nxt][t * 8]);
            gl2lds16(Vt + (size_t)row0 * 1024 + nt0 + kc0 * 8, &Vs[nxt][t * 8]);
        }
        if (kt <= ti) {
            float4v s[4];
#pragma unroll
            for (int nb = 0; nb < 4; nb++) {
                int row = nb * 16 + ln;
                short8 kf0 = *(const short8*)&Ks[cur][((row << 3) | (q ^ (row & 7))) * 8];
                short8 kf1 = *(const short8*)&Ks[cur][((row << 3) | ((4 + q) ^ (row & 7))) * 8];
                s[nb] = (float4v){0.f, 0.f, 0.f, 0.f};
                s[nb] = __builtin_amdgcn_mfma_f32_16x16x32_bf16(kf0, aq0, s[nb], 0, 0, 0);
                s[nb] = __builtin_amdgcn_mfma_f32_16x16x32_bf16(kf1, aq1, s[nb], 0, 0, 0);
            }
            float p[4][4];
            if (kt < ti) {
#pragma unroll
                for (int nb = 0; nb < 4; nb++)
#pragma unroll
                    for (int i = 0; i < 4; i++) p[nb][i] = exp2f(s[nb][i] * CE);
            } else {
#pragma unroll
                for (int nb = 0; nb < 4; nb++)
#pragma unroll
                    for (int i = 0; i < 4; i++) {
                        int tcol = t0 + nb * 16 + q * 4 + i;
                        p[nb][i] = exp2f((tcol <= srow_l) ? s[nb][i] * CE : -1e30f);
                    }
            }
#pragma unroll
            for (int nb = 0; nb < 4; nb++)
                lp += (p[nb][0] + p[nb][1]) + (p[nb][2] + p[nb][3]);
#pragma unroll
            for (int nb = 0; nb < 4; nb++) {
                uint2 pk;
                pk.x = cvt_pk_bf16(p[nb][0], p[nb][1]);
                pk.y = cvt_pk_bf16(p[nb][2], p[nb][3]);
                *(uint2*)&P[w][ln * 76 + nb * 16 + q * 4] = pk;
            }
            asm volatile("s_waitcnt lgkmcnt(0)\n" ::: "memory");
            short8 ap0 = *(const short8*)&P[w][ln * 76 + q * 8];
            short8 ap1 = *(const short8*)&P[w][ln * 76 + 32 + q * 8];
#pragma unroll
            for (int nb = 0; nb < 4; nb++) {
                int row = nb * 16 + ln;
                short8 bv0 = *(const short8*)&Vs[cur][((row << 3) | (q ^ (row & 7))) * 8];
                short8 bv1 = *(const short8*)&Vs[cur][((row << 3) | ((4 + q) ^ (row & 7))) * 8];
                o[nb] = __builtin_amdgcn_mfma_f32_16x16x32_bf16(ap0, bv0, o[nb], 0, 0, 0);
                o[nb] = __builtin_amdgcn_mfma_f32_16x16x32_bf16(ap1, bv1, o[nb], 0, 0, 0);
            }
        }
    }

    // l[srow=ln] lives per-lane; reduce partial sums across the q axis.
    float lred = lp;
    lred += __shfl_xor(lred, 16, 64);
    lred += __shfl_xor(lred, 32, 64);
    // broadcast l for the o-fragment rows (srow = sw + q*4 + i)
    float l_i[4];
#pragma unroll
    for (int i = 0; i < 4; i++)
        l_i[i] = __shfl(lred, (q << 4) | (q * 4 + i), 64);

#pragma unroll
    for (int nb = 0; nb < 4; nb++) {
#pragma unroll
        for (int i = 0; i < 4; i++) {
            int srow = sw + q * 4 + i;
            int d = nb * 16 + ln;
            float z = o[nb][i] / l_i[i];
            int sp = h * 64 + (srow >> 4);
            int ep = ((srow & 15) << 6) + d;
            zp[((size_t)(b * SEQ + sp)) * 1024 + ep] = f2bf(z);
        }
    }
}

// ---------------------------------------------------------------------------
extern "C" void kernel_launch(void* const* d_in, const int* in_sizes, int n_in,
                              void* d_out, int out_size, void* d_ws, size_t ws_size,
                              hipStream_t stream) {
    const void* X  = d_in[0];
    // d_in[1] = mask (causal; applied structurally)
    const void* wq = d_in[2];
    const void* bq = d_in[3];
    const void* wk = d_in[4];
    const void* bk = d_in[5];
    const void* wv = d_in[6];
    const void* bv = d_in[7];
    const void* wo = d_in[8];
    const void* bo = d_in[9];

    char* ws = (char*)d_ws;
    int*    flag  = (int*)ws;                          // [0, 4096)
    ushort* biasq = (ushort*)(ws + 4096);              // 4096 bf16: [bq|bk|bv|bo]
    ushort* WTall = (ushort*)(ws + 12288);             // 4x 1024x1024 bf16 [wq|wk|wv|wo]
    ushort* Xc    = (ushort*)(ws + 8400896);           // 4096x1024 bf16 (fp32 path)
    ushort* QKV   = (ushort*)(ws + 16789504);          // 4096x3072 bf16
    ushort* VT    = (ushort*)(ws + 41955328);          // 64 x 64 x 1024 bf16
    ushort* WTo   = WTall + 3 * 1024 * 1024;
    ushort* ZP    = Xc;                                // alias: Xc dead after QKV gemm

    prep_k<<<5136, 256, 0, stream>>>(X, wq, wk, wv, wo, bq, bk, bv, bo,
                                     Xc, biasq, WTall, flag);
    gemm256_k<<<dim3(12, 16), 512, 0, stream>>>(
        (const ushort*)X, Xc, WTall, biasq, QKV, VT, flag);
    attn_k<<<dim3(8, 64), 512, 0, stream>>>(QKV, VT, ZP);
    gemm_k<64, true, false><<<dim3(8, 64), 256, 0, stream>>>(
        ZP, ZP, WTo, biasq + 3072, d_out, nullptr, flag, 4096, 1024, 1024);
}

// Round 7
// 180.488 us; speedup vs baseline: 1.0225x; 1.0225x over previous
//
#include <hip/hip_runtime.h>
#include <hip/hip_bf16.h>
#include <stdint.h>

typedef __attribute__((ext_vector_type(8))) short short8;
typedef __attribute__((ext_vector_type(4))) float float4v;

#define SEQ   1024
#define NQKV  3072

__device__ __forceinline__ float bf2f(ushort h) {
    union { uint u; float f; } c; c.u = ((uint)h) << 16; return c.f;
}
__device__ __forceinline__ ushort f2bf(float f) {
    union { uint u; float f; } c; c.f = f;
    uint u = c.u;
    return (ushort)((u + 0x7fffu + ((u >> 16) & 1u)) >> 16);
}
__device__ __forceinline__ uint cvt_pk_bf16(float lo, float hi) {
    uint r;
    asm volatile("v_cvt_pk_bf16_f32 %0, %1, %2" : "=v"(r) : "v"(lo), "v"(hi));
    return r;
}
__device__ __forceinline__ void gl2lds16(const ushort* g, ushort* l) {
    __builtin_amdgcn_global_load_lds(
        (const __attribute__((address_space(1))) unsigned int*)(g),
        (__attribute__((address_space(3))) unsigned int*)(l),
        16, 0, 0);
}

#define FENCE() asm volatile("" ::: "memory")

// ---------------------------------------------------------------------------
// prep_k: fused detect + X-convert + bias-concat + 4x weight transpose.
// ---------------------------------------------------------------------------
__global__ __launch_bounds__(256) void prep_k(const void* __restrict__ X,
                                              const void* __restrict__ w0,
                                              const void* __restrict__ w1,
                                              const void* __restrict__ w2,
                                              const void* __restrict__ w3,
                                              const void* __restrict__ bq,
                                              const void* __restrict__ bk,
                                              const void* __restrict__ bv,
                                              const void* __restrict__ bo,
                                              ushort* __restrict__ xc,
                                              ushort* __restrict__ biasout,
                                              ushort* __restrict__ wtall,
                                              int* __restrict__ flag) {
    __shared__ int tot;
    __shared__ ushort tile[64][72];
    int t = threadIdx.x;
    if (t == 0) tot = 0;
    __syncthreads();
    uint wv = ((const uint*)X)[t];
    uint e = (wv >> 7) & 0xFFu;
    bool isbf = (e >= 100u && e <= 130u);
    unsigned long long m = __ballot(isbf);
    if ((t & 63) == 0) atomicAdd(&tot, __popcll(m));
    __syncthreads();
    bool isf = (tot <= 128);   // true -> fp32 input

    int bi = blockIdx.x;
    if (bi == 0 && t == 0) flag[0] = isf ? 1 : 0;

    if (bi < 4096) {
        if (!isf) return;
        int i = (bi * 256 + t) * 4;
        float4 v = *(const float4*)((const float*)X + i);
        ushort4 o;
        o.x = f2bf(v.x); o.y = f2bf(v.y); o.z = f2bf(v.z); o.w = f2bf(v.w);
        *(ushort4*)(xc + i) = o;
    } else if (bi < 4112) {
        int i = (bi - 4096) * 256 + t;
        int sel = i >> 10, j = i & 1023;
        const void* p = (sel == 0) ? bq : (sel == 1) ? bk : (sel == 2) ? bv : bo;
        biasout[i] = isf ? f2bf(((const float*)p)[j]) : ((const ushort*)p)[j];
    } else {
        int idx = bi - 4112;
        int z = idx >> 8, rem = idx & 255;
        const void* in = (z == 0) ? w0 : (z == 1) ? w1 : (z == 2) ? w2 : w3;
        ushort* out = wtall + (size_t)z * 1024 * 1024;
        int k0 = (rem & 15) * 64, n0 = (rem >> 4) * 64;
        int r = t >> 3, c = (t & 7) * 8;
#pragma unroll
        for (int p = 0; p < 2; p++) {
            int rr = r + p * 32;
            if (isf) {
                const float* src = (const float*)in + (size_t)(k0 + rr) * 1024 + n0 + c;
                float4 v0 = *(const float4*)src;
                float4 v1 = *(const float4*)(src + 4);
                tile[rr][c + 0] = f2bf(v0.x); tile[rr][c + 1] = f2bf(v0.y);
                tile[rr][c + 2] = f2bf(v0.z); tile[rr][c + 3] = f2bf(v0.w);
                tile[rr][c + 4] = f2bf(v1.x); tile[rr][c + 5] = f2bf(v1.y);
                tile[rr][c + 6] = f2bf(v1.z); tile[rr][c + 7] = f2bf(v1.w);
            } else {
                uint4 v = *(const uint4*)((const ushort*)in + (size_t)(k0 + rr) * 1024 + n0 + c);
                *(uint4*)&tile[rr][c] = v;
            }
        }
        __syncthreads();
#pragma unroll
        for (int p = 0; p < 2; p++) {
            int n = r + p * 32;
            ushort vals[8];
#pragma unroll
            for (int j = 0; j < 8; j++) vals[j] = tile[c + j][n];
            *(uint4*)(out + (size_t)(n0 + n) * 1024 + k0 + c) = *(uint4*)vals;
        }
    }
}

// ---------------------------------------------------------------------------
// GEMM, BK=32, TRIPLE-BUFFERED LDS with counted vmcnt (T4 retro-fit).
// BM x 128 tile, 4 waves (2x2), 1 barrier per K-iter.
// Mechanism: with 2 buffers the tile consumed at iter kt was issued at
// kt-1 (~400cy earlier) < HBM latency (~900cy), and __syncthreads forces
// vmcnt(0) -> every iter exposes staging latency (m139: counting impossible
// at depth 2). With 3 buffers, tile kt was issued at kt-2 (~800cy) and
// vmcnt(4) leaves tile kt+1's 4 loads in flight across the barrier.
// Ledger (per wave, 4 loads per tile-stage):
//   top of iter kt: outstanding = tile kt (oldest 4) + tile kt+1 (4)
//   -> s_waitcnt vmcnt(4) completes exactly tile kt; s_barrier makes it
//   block-wide. Tail (kt = nIter-1): nothing beyond kt -> vmcnt(0).
//   WAR: stage at iter kt writes buf[(kt+2)%3], last read at iter kt-1;
//   those reads complete (lgkmcnt before their MFMAs) before that wave
//   crosses the kt-top barrier -> safe.
// sched_barrier(0) after the barrier blocks ds_read hoisting (rule #18).
// BK=32 deliberate (R4: BK=64 dropped occupancy, 43.9->48.4). 256-tile
// 4-phase also regressed (R6: 45.9, 1 block/CU). Chunk swizzle slot =
// kc ^ ((row>>1)&3) (conflict-free). T1 XCD swizzle (nwg%8==0: 768, 512).
// K accumulation order unchanged -> bit-identical output.
// WRV: QKV V-third blocks also emit VT[bh][d][t] from the accumulator.
// ---------------------------------------------------------------------------
template <int BM, bool DUAL, bool WRV>
__global__ __launch_bounds__(256) void gemm_k(const ushort* __restrict__ Araw,
                                              const ushort* __restrict__ Aconv,
                                              const ushort* __restrict__ BT,
                                              const ushort* __restrict__ bias,
                                              void* __restrict__ C,
                                              ushort* __restrict__ vt,
                                              const int* __restrict__ flag,
                                              int M, int N, int K) {
    constexpr int RM = BM / 32;   // M-frags per wave
    constexpr int AJ = BM / 64;   // A-chunks per thread (BM*4/256)
    constexpr int ASZ = BM * 32;
    constexpr int BSZ = 128 * 32;
    __shared__ ushort As[3 * ASZ];
    __shared__ ushort Bs[3 * BSZ];
    int nwgx = gridDim.x;
    int orig = blockIdx.y * nwgx + blockIdx.x;
    int cpx = (nwgx * gridDim.y) >> 3;
    int swz = (orig & 7) * cpx + (orig >> 3);
    int n0 = (swz % nwgx) * 128, m0 = (swz / nwgx) * BM;
    int t = threadIdx.x;
    int w = t >> 6, lane = t & 63, q = lane >> 4, ln = lane & 15;
    int wr = w >> 1, wc = w & 1;
    const ushort* A = (*flag) ? Aconv : Araw;

    float4v acc[RM][4];
#pragma unroll
    for (int r = 0; r < RM; r++)
#pragma unroll
        for (int cc = 0; cc < 4; cc++) acc[r][cc] = (float4v){0.f, 0.f, 0.f, 0.f};

    int nIter = K >> 5;

    // stage tile j into slot: 4 gl2lds per thread (AJ + 2)
    // prologue: tiles 0 and 1 into slots 0 and 1 (8 loads outstanding)
#pragma unroll
    for (int pj = 0; pj < 2; pj++) {
        int jk0 = pj << 5;
#pragma unroll
        for (int j = 0; j < AJ; j++) {
            int c = j * 256 + t;
            int row = c >> 2, s = c & 3;
            int kc = s ^ ((row >> 1) & 3);
            gl2lds16(A + (size_t)(m0 + row) * K + jk0 + kc * 8, &As[pj * ASZ + c * 8]);
        }
#pragma unroll
        for (int j = 0; j < 2; j++) {
            int c = j * 256 + t;
            int row = c >> 2, s = c & 3;
            int kc = s ^ ((row >> 1) & 3);
            gl2lds16(BT + (size_t)(n0 + row) * K + jk0 + kc * 8, &Bs[pj * BSZ + c * 8]);
        }
    }

    int cur = 0;          // slot of tile kt
    int stg = 2;          // slot of tile kt+2
    for (int kt = 0; kt < nIter; kt++) {
        if (kt + 1 < nIter) { asm volatile("s_waitcnt vmcnt(4)" ::: "memory"); }
        else                { asm volatile("s_waitcnt vmcnt(0)" ::: "memory"); }
        FENCE();
        __builtin_amdgcn_s_barrier();
        FENCE();
        __builtin_amdgcn_sched_barrier(0);
        if (kt + 2 < nIter) {
            int nk0 = (kt + 2) << 5;
#pragma unroll
            for (int j = 0; j < AJ; j++) {
                int c = j * 256 + t;
                int row = c >> 2, s = c & 3;
                int kc = s ^ ((row >> 1) & 3);
                gl2lds16(A + (size_t)(m0 + row) * K + nk0 + kc * 8, &As[stg * ASZ + c * 8]);
            }
#pragma unroll
            for (int j = 0; j < 2; j++) {
                int c = j * 256 + t;
                int row = c >> 2, s = c & 3;
                int kc = s ^ ((row >> 1) & 3);
                gl2lds16(BT + (size_t)(n0 + row) * K + nk0 + kc * 8, &Bs[stg * BSZ + c * 8]);
            }
        }
        short8 af[RM], bf[4];
#pragma unroll
        for (int r = 0; r < RM; r++) {
            int row = wr * (BM / 2) + r * 16 + ln;
            af[r] = *(const short8*)&As[cur * ASZ + ((row << 2) | (q ^ ((row >> 1) & 3))) * 8];
        }
#pragma unroll
        for (int cc = 0; cc < 4; cc++) {
            int col = wc * 64 + cc * 16 + ln;
            bf[cc] = *(const short8*)&Bs[cur * BSZ + ((col << 2) | (q ^ ((col >> 1) & 3))) * 8];
        }
#pragma unroll
        for (int r = 0; r < RM; r++)
#pragma unroll
            for (int cc = 0; cc < 4; cc++)
                acc[r][cc] = __builtin_amdgcn_mfma_f32_16x16x32_bf16(af[r], bf[cc], acc[r][cc], 0, 0, 0);
        cur = (cur == 2) ? 0 : cur + 1;
        stg = (stg == 2) ? 0 : stg + 1;
    }

    bool outf = DUAL && (*flag != 0);
    bool wrv = WRV && (n0 >= 2048);
#pragma unroll
    for (int cc = 0; cc < 4; cc++) {
        int n = n0 + wc * 64 + cc * 16 + ln;
        float bs = bf2f(bias[n]);
#pragma unroll
        for (int r = 0; r < RM; r++) {
            ushort pk[4];
#pragma unroll
            for (int i = 0; i < 4; i++) {
                int m = m0 + wr * (BM / 2) + r * 16 + q * 4 + i;
                float v = acc[r][cc][i] + bs;
                if (outf) ((float*)C)[(size_t)m * N + n] = v;
                else      ((ushort*)C)[(size_t)m * N + n] = f2bf(v);
                pk[i] = f2bf(v);
            }
            if (wrv) {
                int mb = m0 + wr * (BM / 2) + r * 16 + q * 4;   // 4 consecutive tokens
                int b = mb >> 10, trow = mb & 1023;
                int h = (n - 2048) >> 6, d = n & 63;
                *(ushort4*)(vt + (((size_t)(b * 16 + h) * 64 + d) * 1024 + trow)) = *(ushort4*)pk;
            }
        }
    }
}

// ---------------------------------------------------------------------------
// Flash attention, causal, WAVE-SPLIT shared-prefix dual-tile (pr, 15-pr),
// pipelined, no-max softmax. Balanced: 17 active wave-group iters per block;
// CU-pairing balance via pr = 7-x relabel for bh>=32 (R5-verified, -2.9us).
// Do NOT pair adjacent tiles (R3 regression +7.6us). No setprio (m190).
// SWAPPED QK^T (T12); P-write via v_cvt_pk_bf16_f32 pairs.
// Faithful reshape: z[b,h,s,d] -> Z'[b][h*64 + s/16][(s%16)*64 + d]
// ---------------------------------------------------------------------------
__global__ __launch_bounds__(512) void attn_k(const ushort* __restrict__ qkv,
                                              const ushort* __restrict__ vt,
                                              ushort* __restrict__ zp) {
    __shared__ ushort Ks[2][64 * 64];
    __shared__ ushort Vs[2][64 * 64];
    __shared__ ushort P[8][16 * 76];
    int bh = blockIdx.y;
    int pr = (bh & 32) ? (7 - blockIdx.x) : blockIdx.x;
    int b = bh >> 4, h = bh & 15;
    int t = threadIdx.x;
    int w = t >> 6;
    int grp = w >> 2;
    int lane = t & 63, q = lane >> 4, ln = lane & 15;

    const float CE = 0.72134752f;    // 0.5 * log2(e)

    const ushort* Qp = qkv + (size_t)(b * SEQ) * NQKV + h * 64;
    const ushort* Kp = qkv + (size_t)(b * SEQ) * NQKV + 1024 + h * 64;
    const ushort* Vt = vt + (size_t)bh * 64 * 1024;

    int row0 = t >> 3, kc0 = (t & 7) ^ (row0 & 7);

    int tiB = 15 - pr;
    int ti = grp ? tiB : pr;
    int sw = ti * 64 + (w & 3) * 16;

    short8 aq0 = *(const short8*)(Qp + (size_t)(sw + ln) * NQKV + q * 8);
    short8 aq1 = *(const short8*)(Qp + (size_t)(sw + ln) * NQKV + 32 + q * 8);

    float lp = 0.f;
    float4v o[4];
#pragma unroll
    for (int nb = 0; nb < 4; nb++) o[nb] = (float4v){0.f, 0.f, 0.f, 0.f};

    gl2lds16(Kp + (size_t)row0 * NQKV + kc0 * 8, &Ks[0][t * 8]);
    gl2lds16(Vt + (size_t)row0 * 1024 + kc0 * 8, &Vs[0][t * 8]);

    int srow_l = sw + ln;   // this lane's q-row (post-swap: srow = ln axis)

    for (int kt = 0; kt <= tiB; kt++) {
        int cur = kt & 1;
        int t0 = kt * 64;
        __syncthreads();
        if (kt < tiB) {
            int nt0 = t0 + 64, nxt = cur ^ 1;
            gl2lds16(Kp + (size_t)(nt0 + row0) * NQKV + kc0 * 8, &Ks[nxt][t * 8]);
            gl2lds16(Vt + (size_t)row0 * 1024 + nt0 + kc0 * 8, &Vs[nxt][t * 8]);
        }
        if (kt <= ti) {
            float4v s[4];
#pragma unroll
            for (int nb = 0; nb < 4; nb++) {
                int row = nb * 16 + ln;
                short8 kf0 = *(const short8*)&Ks[cur][((row << 3) | (q ^ (row & 7))) * 8];
                short8 kf1 = *(const short8*)&Ks[cur][((row << 3) | ((4 + q) ^ (row & 7))) * 8];
                s[nb] = (float4v){0.f, 0.f, 0.f, 0.f};
                s[nb] = __builtin_amdgcn_mfma_f32_16x16x32_bf16(kf0, aq0, s[nb], 0, 0, 0);
                s[nb] = __builtin_amdgcn_mfma_f32_16x16x32_bf16(kf1, aq1, s[nb], 0, 0, 0);
            }
            float p[4][4];
            if (kt < ti) {
#pragma unroll
                for (int nb = 0; nb < 4; nb++)
#pragma unroll
                    for (int i = 0; i < 4; i++) p[nb][i] = exp2f(s[nb][i] * CE);
            } else {
#pragma unroll
                for (int nb = 0; nb < 4; nb++)
#pragma unroll
                    for (int i = 0; i < 4; i++) {
                        int tcol = t0 + nb * 16 + q * 4 + i;
                        p[nb][i] = exp2f((tcol <= srow_l) ? s[nb][i] * CE : -1e30f);
                    }
            }
#pragma unroll
            for (int nb = 0; nb < 4; nb++)
                lp += (p[nb][0] + p[nb][1]) + (p[nb][2] + p[nb][3]);
#pragma unroll
            for (int nb = 0; nb < 4; nb++) {
                uint2 pk;
                pk.x = cvt_pk_bf16(p[nb][0], p[nb][1]);
                pk.y = cvt_pk_bf16(p[nb][2], p[nb][3]);
                *(uint2*)&P[w][ln * 76 + nb * 16 + q * 4] = pk;
            }
            asm volatile("s_waitcnt lgkmcnt(0)\n" ::: "memory");
            short8 ap0 = *(const short8*)&P[w][ln * 76 + q * 8];
            short8 ap1 = *(const short8*)&P[w][ln * 76 + 32 + q * 8];
#pragma unroll
            for (int nb = 0; nb < 4; nb++) {
                int row = nb * 16 + ln;
                short8 bv0 = *(const short8*)&Vs[cur][((row << 3) | (q ^ (row & 7))) * 8];
                short8 bv1 = *(const short8*)&Vs[cur][((row << 3) | ((4 + q) ^ (row & 7))) * 8];
                o[nb] = __builtin_amdgcn_mfma_f32_16x16x32_bf16(ap0, bv0, o[nb], 0, 0, 0);
                o[nb] = __builtin_amdgcn_mfma_f32_16x16x32_bf16(ap1, bv1, o[nb], 0, 0, 0);
            }
        }
    }

    // l[srow=ln] lives per-lane; reduce partial sums across the q axis.
    float lred = lp;
    lred += __shfl_xor(lred, 16, 64);
    lred += __shfl_xor(lred, 32, 64);
    // broadcast l for the o-fragment rows (srow = sw + q*4 + i)
    float l_i[4];
#pragma unroll
    for (int i = 0; i < 4; i++)
        l_i[i] = __shfl(lred, (q << 4) | (q * 4 + i), 64);

#pragma unroll
    for (int nb = 0; nb < 4; nb++) {
#pragma unroll
        for (int i = 0; i < 4; i++) {
            int srow = sw + q * 4 + i;
            int d = nb * 16 + ln;
            float z = o[nb][i] / l_i[i];
            int sp = h * 64 + (srow >> 4);
            int ep = ((srow & 15) << 6) + d;
            zp[((size_t)(b * SEQ + sp)) * 1024 + ep] = f2bf(z);
        }
    }
}

// ---------------------------------------------------------------------------
extern "C" void kernel_launch(void* const* d_in, const int* in_sizes, int n_in,
                              void* d_out, int out_size, void* d_ws, size_t ws_size,
                              hipStream_t stream) {
    const void* X  = d_in[0];
    // d_in[1] = mask (causal; applied structurally)
    const void* wq = d_in[2];
    const void* bq = d_in[3];
    const void* wk = d_in[4];
    const void* bk = d_in[5];
    const void* wv = d_in[6];
    const void* bv = d_in[7];
    const void* wo = d_in[8];
    const void* bo = d_in[9];

    char* ws = (char*)d_ws;
    int*    flag  = (int*)ws;                          // [0, 4096)
    ushort* biasq = (ushort*)(ws + 4096);              // 4096 bf16: [bq|bk|bv|bo]
    ushort* WTall = (ushort*)(ws + 12288);             // 4x 1024x1024 bf16 [wq|wk|wv|wo]
    ushort* Xc    = (ushort*)(ws + 8400896);           // 4096x1024 bf16 (fp32 path)
    ushort* QKV   = (ushort*)(ws + 16789504);          // 4096x3072 bf16
    ushort* VT    = (ushort*)(ws + 41955328);          // 64 x 64 x 1024 bf16
    ushort* WTo   = WTall + 3 * 1024 * 1024;
    ushort* ZP    = Xc;                                // alias: Xc dead after QKV gemm

    prep_k<<<5136, 256, 0, stream>>>(X, wq, wk, wv, wo, bq, bk, bv, bo,
                                     Xc, biasq, WTall, flag);
    gemm_k<128, false, true><<<dim3(24, 32), 256, 0, stream>>>(
        (const ushort*)X, Xc, WTall, biasq, QKV, VT, flag, 4096, NQKV, 1024);
    attn_k<<<dim3(8, 64), 512, 0, stream>>>(QKV, VT, ZP);
    gemm_k<64, true, false><<<dim3(8, 64), 256, 0, stream>>>(
        ZP, ZP, WTo, biasq + 3072, d_out, nullptr, flag, 4096, 1024, 1024);
}